// Round 4
// baseline (480.977 us; speedup 1.0000x reference)
//
#include <hip/hip_runtime.h>
#include <hip/hip_bf16.h>
#include <math.h>

#define D_MODEL 1024
#define NH 16
#define HD 64
#define TMAX 2048
#define DFF 4096
#define NB 64
#define ACS 128                 // attention chunk size (positions per block)
#define NC (TMAX / ACS)         // 16 chunks max

// ---- split-K GEMM partial with float4-n accumulation ------------------------
// Tile: (NQ*4) columns x 64 batches x KC k's. 256 threads.
// thread: nq = tid % NQ (n-quad), bg = tid / NQ (batch group of BPG batches).
template<int KC, int NQ>
__global__ void gemm_part(const float* __restrict__ X,
                          const float* __restrict__ W,
                          float* __restrict__ P,
                          int K, int N) {
    constexpr int BPG = 64 * NQ / 256;          // batches per thread
    const int nq = threadIdx.x % NQ;
    const int bg = threadIdx.x / NQ;
    const int n  = blockIdx.x * NQ * 4 + nq * 4;
    const int k0 = blockIdx.y * KC;

    __shared__ float Xs[64][KC + 4];            // +4 pad: kills bank conflicts for NQ=16

    for (int idx = threadIdx.x; idx < 64 * (KC / 4); idx += 256) {
        const int b  = idx / (KC / 4);
        const int kk = (idx % (KC / 4)) * 4;
        *reinterpret_cast<float4*>(&Xs[b][kk]) =
            *reinterpret_cast<const float4*>(&X[(size_t)b * K + k0 + kk]);
    }
    __syncthreads();

    float4 acc[BPG];
#pragma unroll
    for (int i = 0; i < BPG; ++i) acc[i] = make_float4(0.f, 0.f, 0.f, 0.f);

    const float* Wp = W + (size_t)k0 * N + n;
    for (int kk = 0; kk < KC; kk += 4) {
        const float4 w0 = *reinterpret_cast<const float4*>(&Wp[(size_t)(kk+0) * N]);
        const float4 w1 = *reinterpret_cast<const float4*>(&Wp[(size_t)(kk+1) * N]);
        const float4 w2 = *reinterpret_cast<const float4*>(&Wp[(size_t)(kk+2) * N]);
        const float4 w3 = *reinterpret_cast<const float4*>(&Wp[(size_t)(kk+3) * N]);
#pragma unroll
        for (int i = 0; i < BPG; ++i) {
            const float4 xv = *reinterpret_cast<const float4*>(&Xs[bg * BPG + i][kk]);
            acc[i].x += xv.x*w0.x + xv.y*w1.x + xv.z*w2.x + xv.w*w3.x;
            acc[i].y += xv.x*w0.y + xv.y*w1.y + xv.z*w2.y + xv.w*w3.y;
            acc[i].z += xv.x*w0.z + xv.y*w1.z + xv.z*w2.z + xv.w*w3.z;
            acc[i].w += xv.x*w0.w + xv.y*w1.w + xv.z*w2.w + xv.w*w3.w;
        }
    }

    float* Pp = P + (size_t)blockIdx.y * 64 * N + n;
#pragma unroll
    for (int i = 0; i < BPG; ++i)
        *reinterpret_cast<float4*>(&Pp[(size_t)(bg * BPG + i) * N]) = acc[i];
}

// ---- reduce S partials + bias (+relu) -> Y[64,N] ----------------------------
template<bool RELU>
__global__ void reduce_kernel(const float* __restrict__ P,
                              const float* __restrict__ bias,
                              float* __restrict__ Y,
                              int N, int S) {
    const int i = blockIdx.x * 256 + threadIdx.x;   // over 64*N
    const int n = i % N;
    float s = 0.0f;
    for (int ss = 0; ss < S; ++ss)
        s += P[(size_t)ss * 64 * N + i];
    s += bias[n];
    if (RELU)  s = fmaxf(s, 0.0f);
    Y[i] = s;
}

// ---- fused: reduce S partials + bias + resid, then LayerNorm -> Y[64,1024] --
// one block per batch row; 256 threads, 4 n's each.
template<int S>
__global__ void reduce_ln_kernel(const float* __restrict__ P,
                                 const float* __restrict__ bias,
                                 const float* __restrict__ resid,
                                 const float* __restrict__ lnw,
                                 const float* __restrict__ lnb,
                                 float* __restrict__ Y) {
    const int b   = blockIdx.x;
    const int tid = threadIdx.x;
    float v[4];
    float s = 0.f, sq = 0.f;
#pragma unroll
    for (int jj = 0; jj < 4; ++jj) {
        const int n = jj * 256 + tid;
        float t = bias[n] + resid[(size_t)b * D_MODEL + n];
#pragma unroll
        for (int ss = 0; ss < S; ++ss)
            t += P[((size_t)ss * 64 + b) * D_MODEL + n];
        v[jj] = t; s += t; sq += t * t;
    }
    for (int off = 1; off < 64; off <<= 1) {
        s  += __shfl_xor(s, off);
        sq += __shfl_xor(sq, off);
    }
    __shared__ float rs[4], rq[4];
    const int wave = tid >> 6;
    if ((tid & 63) == 0) { rs[wave] = s; rq[wave] = sq; }
    __syncthreads();
    s  = rs[0] + rs[1] + rs[2] + rs[3];
    sq = rq[0] + rq[1] + rq[2] + rq[3];
    const float mean = s * (1.0f / D_MODEL);
    const float var  = sq * (1.0f / D_MODEL) - mean * mean;
    const float rstd = rsqrtf(var + 1e-5f);
#pragma unroll
    for (int jj = 0; jj < 4; ++jj) {
        const int n = jj * 256 + tid;
        Y[(size_t)b * D_MODEL + n] = (v[jj] - mean) * rstd * lnw[n] + lnb[n];
    }
}

// ---- flash-decode partial: one block per (b, h, chunk) ----------------------
__global__ void attn_part(const float* __restrict__ qkv,
                          const float* __restrict__ k_cache,
                          const float* __restrict__ v_cache,
                          const int* __restrict__ kv_len,
                          float* __restrict__ m_ws,
                          float* __restrict__ s_ws,
                          float* __restrict__ o_ws) {
    const int b = blockIdx.x;
    const int h = blockIdx.y;
    const int c = blockIdx.z;
    const int tid = threadIdx.x; // 256

    const int L  = kv_len[b];
    const int nt = L + 1;
    const int c0 = c * ACS;
    if (c0 >= nt) return;                       // inactive chunk: no writes
    const int tend = min(ACS, nt - c0);
    const bool full = (c0 + ACS <= L);          // all rows from cache, chunk full

    __shared__ float q_s[HD];
    __shared__ float p_s[ACS];
    __shared__ float red[8];
    __shared__ float ored[16][HD];

    const float* qkv_row = qkv + (size_t)b * (3 * D_MODEL);
    if (tid < HD) q_s[tid] = qkv_row[h * HD + tid] * 0.125f; // 1/sqrt(64)
    __syncthreads();

    const size_t bh = ((size_t)b * NH + h) * (size_t)TMAX * HD;
    const float* kc   = k_cache + bh + (size_t)c0 * HD;
    const float* vc   = v_cache + bh + (size_t)c0 * HD;
    const float* knew = qkv_row + D_MODEL     + h * HD;
    const float* vnew = qkv_row + 2 * D_MODEL + h * HD;
    const int Lloc = L - c0;

    // ---- scores: 16 lanes per row (wave covers 4 contiguous rows = 1KB/inst)
    const int rg = tid >> 4, l16 = tid & 15;
    const float4 qf = *reinterpret_cast<const float4*>(&q_s[l16 * 4]);
    if (full) {
#pragma unroll
        for (int j = 0; j < ACS / 16; ++j) {
            const int t = rg + j * 16;
            const float4 kf = *reinterpret_cast<const float4*>(&kc[(size_t)t * HD + l16 * 4]);
            float d = qf.x*kf.x + qf.y*kf.y + qf.z*kf.z + qf.w*kf.w;
            d += __shfl_xor(d, 1);
            d += __shfl_xor(d, 2);
            d += __shfl_xor(d, 4);
            d += __shfl_xor(d, 8);
            if (l16 == 0) p_s[t] = d;
        }
    } else {
        for (int t = rg; t < tend; t += 16) {
            const float* krow = (t == Lloc) ? knew : (kc + (size_t)t * HD);
            const float4 kf = *reinterpret_cast<const float4*>(&krow[l16 * 4]);
            float d = qf.x*kf.x + qf.y*kf.y + qf.z*kf.z + qf.w*kf.w;
            d += __shfl_xor(d, 1);
            d += __shfl_xor(d, 2);
            d += __shfl_xor(d, 4);
            d += __shfl_xor(d, 8);
            if (l16 == 0) p_s[t] = d;
        }
    }
    __syncthreads();

    // ---- local softmax stats ----
    float m = -INFINITY;
    for (int t = tid; t < tend; t += 256) m = fmaxf(m, p_s[t]);
    for (int off = 1; off < 64; off <<= 1) m = fmaxf(m, __shfl_xor(m, off));
    const int wave = tid >> 6;
    if ((tid & 63) == 0) red[wave] = m;
    __syncthreads();
    m = fmaxf(fmaxf(red[0], red[1]), fmaxf(red[2], red[3]));

    float s = 0.0f;
    for (int t = tid; t < tend; t += 256) {
        const float e = expf(p_s[t] - m);
        p_s[t] = e;
        s += e;
    }
    for (int off = 1; off < 64; off <<= 1) s += __shfl_xor(s, off);
    if ((tid & 63) == 0) red[4 + wave] = s;
    __syncthreads();
    const float ssum = red[4] + red[5] + red[6] + red[7];

    // ---- unnormalized P@V: 16 lanes per row, float4 per lane ----
    const int d4 = tid & 15, r = tid >> 4;
    float4 acc = make_float4(0.f, 0.f, 0.f, 0.f);
    if (full) {
#pragma unroll
        for (int j = 0; j < ACS / 16; ++j) {
            const int t = r + j * 16;
            const float4 vv = *reinterpret_cast<const float4*>(&vc[(size_t)t * HD + d4 * 4]);
            const float p = p_s[t];
            acc.x += p * vv.x; acc.y += p * vv.y; acc.z += p * vv.z; acc.w += p * vv.w;
        }
    } else {
        for (int t = r; t < tend; t += 16) {
            const float* vrow = (t == Lloc) ? vnew : (vc + (size_t)t * HD);
            const float4 vv = *reinterpret_cast<const float4*>(&vrow[d4 * 4]);
            const float p = p_s[t];
            acc.x += p * vv.x; acc.y += p * vv.y; acc.z += p * vv.z; acc.w += p * vv.w;
        }
    }
    *reinterpret_cast<float4*>(&ored[r][d4 * 4]) = acc;
    __syncthreads();

    const size_t idx = ((size_t)b * NH + h) * NC + c;
    if (tid == 0) { m_ws[idx] = m; s_ws[idx] = ssum; }
    if (tid < HD) {
        float o = 0.0f;
#pragma unroll
        for (int g = 0; g < 16; ++g) o += ored[g][tid];
        o_ws[idx * HD + tid] = o;
    }
}

// ---- combine chunk partials -> o[b, h*HD + d] -------------------------------
__global__ void attn_combine(const float* __restrict__ m_ws,
                             const float* __restrict__ s_ws,
                             const float* __restrict__ o_ws,
                             const int* __restrict__ kv_len,
                             float* __restrict__ o) {
    const int b = blockIdx.x;
    const int h = blockIdx.y;
    const int d = threadIdx.x;  // 64
    const int nt = kv_len[b] + 1;
    const int nc = (nt + ACS - 1) / ACS;
    const size_t idx0 = ((size_t)b * NH + h) * NC;

    float M = -INFINITY;
    for (int c = 0; c < nc; ++c) M = fmaxf(M, m_ws[idx0 + c]);
    float den = 0.0f, num = 0.0f;
    for (int c = 0; c < nc; ++c) {
        const float w = expf(m_ws[idx0 + c] - M);
        den += w * s_ws[idx0 + c];
        num += w * o_ws[(idx0 + c) * HD + d];
    }
    o[(size_t)b * D_MODEL + h * HD + d] = num / den;
}

extern "C" void kernel_launch(void* const* d_in, const int* in_sizes, int n_in,
                              void* d_out, int out_size, void* d_ws, size_t ws_size,
                              hipStream_t stream) {
    const float* x       = (const float*)d_in[0];
    const float* k_cache = (const float*)d_in[1];
    const float* v_cache = (const float*)d_in[2];
    const int*   kv_len  = (const int*)d_in[4];
    const float* qkv_w   = (const float*)d_in[6];
    const float* qkv_b   = (const float*)d_in[7];
    const float* out_w   = (const float*)d_in[8];
    const float* out_b   = (const float*)d_in[9];
    const float* ln1_w   = (const float*)d_in[10];
    const float* ln1_b   = (const float*)d_in[11];
    const float* ln2_w   = (const float*)d_in[12];
    const float* ln2_b   = (const float*)d_in[13];
    const float* mlp_w1  = (const float*)d_in[14];
    const float* mlp_b1  = (const float*)d_in[15];
    const float* mlp_w2  = (const float*)d_in[16];
    const float* mlp_b2  = (const float*)d_in[17];

    float* out = (float*)d_out;
    float* ws  = (float*)d_ws;
    float* qkv = ws;                  // 64*3072 = 196608
    float* o   = ws + 196608;         // 64*1024
    float* t2  = ws + 262144;         // 64*1024
    float* t3  = ws + 327680;         // 64*4096
    float* P   = ws + 589824;         // up to 16*64*3072 = 3145728 floats
    // attention partials alias P (disjoint in time):
    float* m_ws = P;                          // 16384
    float* s_ws = P + 16384;                  // 16384
    float* o_ws = P + 32768;                  // 1048576

    // ---- qkv = x @ qkv_w + qkv_b : K=1024, N=3072, KC=64 -> S=16 ----
    gemm_part<64, 64><<<dim3(12, 16), 256, 0, stream>>>(x, qkv_w, P, 1024, 3072);
    reduce_kernel<false><<<768, 256, 0, stream>>>(P, qkv_b, qkv, 3072, 16);

    // ---- attention (flash-decode over 16 chunks of 128) ----
    attn_part<<<dim3(NB, NH, NC), 256, 0, stream>>>(qkv, k_cache, v_cache, kv_len, m_ws, s_ws, o_ws);
    attn_combine<<<dim3(NB, NH), 64, 0, stream>>>(m_ws, s_ws, o_ws, kv_len, o);

    // ---- t1 = x + o @ out_w + out_b ; t2 = LN1(t1) : K=1024, N=1024 ----
    gemm_part<64, 16><<<dim3(16, 16), 256, 0, stream>>>(o, out_w, P, 1024, 1024);
    reduce_ln_kernel<16><<<64, 256, 0, stream>>>(P, out_b, x, ln1_w, ln1_b, t2);

    // ---- t3 = relu(t2 @ mlp_w1 + mlp_b1) : K=1024, N=4096, KC=64 -> S=16 ----
    gemm_part<64, 64><<<dim3(16, 16), 256, 0, stream>>>(t2, mlp_w1, P, 1024, 4096);
    reduce_kernel<true><<<1024, 256, 0, stream>>>(P, mlp_b1, t3, 4096, 16);

    // ---- t4 = t2 + t3 @ mlp_w2 + mlp_b2 ; out = LN2(t4) : K=4096, N=1024 ----
    gemm_part<128, 16><<<dim3(16, 32), 256, 0, stream>>>(t3, mlp_w2, P, 4096, 1024);
    reduce_ln_kernel<32><<<64, 256, 0, stream>>>(P, mlp_b2, t2, ln2_w, ln2_b, out);
}

// Round 5
// 304.360 us; speedup vs baseline: 1.5803x; 1.5803x over previous
//
#include <hip/hip_runtime.h>
#include <hip/hip_bf16.h>
#include <math.h>

#define D_MODEL 1024
#define NH 16
#define HD 64
#define TMAX 2048
#define DFF 4096
#define NB 64
#define ACS 256                 // attention chunk size (positions per block)
#define NC (TMAX / ACS)         // 8 chunks max

// ---- split-K GEMM partial: P[s][64][N] = X[64, k0:k0+KC] @ W[k0:k0+KC, N] ----
// (round-3 verbatim — measured-good)
template<int KC>
__global__ void gemm64_part(const float* __restrict__ X,
                            const float* __restrict__ W,
                            float* __restrict__ P,
                            int K, int N) {
    const int tx = threadIdx.x & 63;
    const int ty = threadIdx.x >> 6;          // 0..3
    const int n  = blockIdx.x * 64 + tx;
    const int k0 = blockIdx.y * KC;

    __shared__ float Xs[64][KC];

    for (int idx = threadIdx.x; idx < 64 * (KC / 4); idx += 256) {
        const int b  = idx / (KC / 4);
        const int kk = (idx % (KC / 4)) * 4;
        *reinterpret_cast<float4*>(&Xs[b][kk]) =
            *reinterpret_cast<const float4*>(&X[(size_t)b * K + k0 + kk]);
    }
    __syncthreads();

    float acc[16] = {0.f,0.f,0.f,0.f,0.f,0.f,0.f,0.f,
                     0.f,0.f,0.f,0.f,0.f,0.f,0.f,0.f};
    const float* Wp = W + (size_t)k0 * N + n;
    for (int kk = 0; kk < KC; kk += 4) {
        const float w0 = Wp[(size_t)(kk+0) * N];
        const float w1 = Wp[(size_t)(kk+1) * N];
        const float w2 = Wp[(size_t)(kk+2) * N];
        const float w3 = Wp[(size_t)(kk+3) * N];
#pragma unroll
        for (int i = 0; i < 16; ++i) {
            const float4 xv = *reinterpret_cast<const float4*>(&Xs[ty*16 + i][kk]);
            acc[i] += xv.x*w0 + xv.y*w1 + xv.z*w2 + xv.w*w3;
        }
    }

    float* Pp = P + (size_t)blockIdx.y * 64 * N + n;
#pragma unroll
    for (int i = 0; i < 16; ++i)
        Pp[(size_t)(ty*16 + i) * N] = acc[i];
}

// ---- reduce S partials + bias (+resid) (+relu) -> Y[64,N] -------------------
template<bool RELU, bool RESID>
__global__ void reduce_kernel(const float* __restrict__ P,
                              const float* __restrict__ bias,
                              const float* __restrict__ resid,
                              float* __restrict__ Y,
                              int N, int S) {
    const int i = blockIdx.x * 256 + threadIdx.x;   // over 64*N
    const int n = i % N;
    float s = 0.0f;
    for (int ss = 0; ss < S; ++ss)
        s += P[(size_t)ss * 64 * N + i];
    s += bias[n];
    if (RESID) s += resid[i];
    if (RELU)  s = fmaxf(s, 0.0f);
    Y[i] = s;
}

// ---- flash-decode partial: one block per (b, h, chunk of 256) ---------------
// K rows register-batched (16 indep float4 loads); V prefetched to registers
// before softmax so its HBM latency hides under the reductions.
__global__ void attn_part(const float* __restrict__ qkv,
                          const float* __restrict__ k_cache,
                          const float* __restrict__ v_cache,
                          const int* __restrict__ kv_len,
                          float* __restrict__ m_ws,
                          float* __restrict__ s_ws,
                          float* __restrict__ o_ws) {
    const int b = blockIdx.x;
    const int h = blockIdx.y;
    const int c = blockIdx.z;
    const int tid = threadIdx.x; // 256

    const int L  = kv_len[b];
    const int nt = L + 1;
    const int c0 = c * ACS;
    if (c0 >= nt) return;                       // inactive chunk: no writes
    const int tend = min(ACS, nt - c0);
    const bool full = (c0 + ACS <= L);          // all 256 rows straight from cache

    __shared__ float q_s[HD];
    __shared__ float p_s[ACS];
    __shared__ float red[8];
    __shared__ float ored[16][HD + 4];

    const float* qkv_row = qkv + (size_t)b * (3 * D_MODEL);
    if (tid < HD) q_s[tid] = qkv_row[h * HD + tid] * 0.125f; // 1/sqrt(64)
    __syncthreads();

    const size_t bh = ((size_t)b * NH + h) * (size_t)TMAX * HD;
    const float* kc   = k_cache + bh + (size_t)c0 * HD;
    const float* vc   = v_cache + bh + (size_t)c0 * HD;
    const float* knew = qkv_row + D_MODEL     + h * HD;
    const float* vnew = qkv_row + 2 * D_MODEL + h * HD;
    const int Lloc = L - c0;

    // ---- scores: 16 lanes per row; rows rg, rg+16, ..., rg+240 ----
    const int rg = tid >> 4, l16 = tid & 15;
    const float4 qf = *reinterpret_cast<const float4*>(&q_s[l16 * 4]);
    if (full) {
        float4 kf[16];
#pragma unroll
        for (int j = 0; j < 16; ++j)
            kf[j] = *reinterpret_cast<const float4*>(&kc[(size_t)(rg + j * 16) * HD + l16 * 4]);
#pragma unroll
        for (int j = 0; j < 16; ++j) {
            float d = qf.x*kf[j].x + qf.y*kf[j].y + qf.z*kf[j].z + qf.w*kf[j].w;
            d += __shfl_xor(d, 1);
            d += __shfl_xor(d, 2);
            d += __shfl_xor(d, 4);
            d += __shfl_xor(d, 8);
            if (l16 == 0) p_s[rg + j * 16] = d;
        }
    } else {
        for (int t = rg; t < tend; t += 16) {
            const float* krow = (t == Lloc) ? knew : (kc + (size_t)t * HD);
            const float4 kf = *reinterpret_cast<const float4*>(&krow[l16 * 4]);
            float d = qf.x*kf.x + qf.y*kf.y + qf.z*kf.z + qf.w*kf.w;
            d += __shfl_xor(d, 1);
            d += __shfl_xor(d, 2);
            d += __shfl_xor(d, 4);
            d += __shfl_xor(d, 8);
            if (l16 == 0) p_s[t] = d;
        }
    }

    // ---- V prefetch to registers (independent of scores/softmax) ----
    const int d4 = tid & 15, r = tid >> 4;      // dim-quad, row-in-stride
    float4 vreg[16];
    if (full) {
#pragma unroll
        for (int j = 0; j < 16; ++j)
            vreg[j] = *reinterpret_cast<const float4*>(&vc[(size_t)(r + j * 16) * HD + d4 * 4]);
    } else {
#pragma unroll
        for (int j = 0; j < 16; ++j) {
            const int t = r + j * 16;
            if (t < tend) {
                const float* vrow = (t == Lloc) ? vnew : (vc + (size_t)t * HD);
                vreg[j] = *reinterpret_cast<const float4*>(&vrow[d4 * 4]);
            } else {
                vreg[j] = make_float4(0.f, 0.f, 0.f, 0.f);
            }
        }
    }
    __syncthreads();    // p_s complete

    // ---- softmax stats: exactly one element per thread ----
    const float pv = (tid < tend) ? p_s[tid] : -INFINITY;
    float m = pv;
    for (int off = 1; off < 64; off <<= 1) m = fmaxf(m, __shfl_xor(m, off));
    const int wave = tid >> 6;
    if ((tid & 63) == 0) red[wave] = m;
    __syncthreads();
    m = fmaxf(fmaxf(red[0], red[1]), fmaxf(red[2], red[3]));

    float e = (tid < tend) ? expf(pv - m) : 0.0f;
    p_s[tid] = e;                                // zero-fill beyond tend
    float s = e;
    for (int off = 1; off < 64; off <<= 1) s += __shfl_xor(s, off);
    if ((tid & 63) == 0) red[4 + wave] = s;
    __syncthreads();
    const float ssum = red[4] + red[5] + red[6] + red[7];

    // ---- unnormalized P@V from registers ----
    float4 acc = make_float4(0.f, 0.f, 0.f, 0.f);
#pragma unroll
    for (int j = 0; j < 16; ++j) {
        const float p = p_s[r + j * 16];
        acc.x += p * vreg[j].x; acc.y += p * vreg[j].y;
        acc.z += p * vreg[j].z; acc.w += p * vreg[j].w;
    }
    *reinterpret_cast<float4*>(&ored[r][d4 * 4]) = acc;
    __syncthreads();

    const size_t idx = ((size_t)b * NH + h) * NC + c;
    if (tid == 0) { m_ws[idx] = m; s_ws[idx] = ssum; }
    if (tid < HD) {
        float o = 0.0f;
#pragma unroll
        for (int g = 0; g < 16; ++g) o += ored[g][tid];
        o_ws[idx * HD + tid] = o;
    }
}

// ---- combine chunk partials -> o[b, h*HD + d] -------------------------------
__global__ void attn_combine(const float* __restrict__ m_ws,
                             const float* __restrict__ s_ws,
                             const float* __restrict__ o_ws,
                             const int* __restrict__ kv_len,
                             float* __restrict__ o) {
    const int b = blockIdx.x;
    const int h = blockIdx.y;
    const int d = threadIdx.x;  // 64
    const int nt = kv_len[b] + 1;
    const int nc = (nt + ACS - 1) / ACS;
    const size_t idx0 = ((size_t)b * NH + h) * NC;

    float M = -INFINITY;
    for (int c = 0; c < nc; ++c) M = fmaxf(M, m_ws[idx0 + c]);
    float den = 0.0f, num = 0.0f;
    for (int c = 0; c < nc; ++c) {
        const float w = expf(m_ws[idx0 + c] - M);
        den += w * s_ws[idx0 + c];
        num += w * o_ws[(idx0 + c) * HD + d];
    }
    o[(size_t)b * D_MODEL + h * HD + d] = num / den;
}

// ---------------- LayerNorm over D=1024, one block per row ------------------
__global__ void ln_kernel(const float* __restrict__ X,
                          const float* __restrict__ w,
                          const float* __restrict__ b,
                          float* __restrict__ Y) {
    const int row = blockIdx.x;
    const int tid = threadIdx.x; // 256, each handles 4 elems
    const float4 xv = *reinterpret_cast<const float4*>(&X[(size_t)row * D_MODEL + tid * 4]);
    float s  = xv.x + xv.y + xv.z + xv.w;
    float sq = xv.x*xv.x + xv.y*xv.y + xv.z*xv.z + xv.w*xv.w;
    for (int off = 1; off < 64; off <<= 1) {
        s  += __shfl_xor(s, off);
        sq += __shfl_xor(sq, off);
    }
    __shared__ float rs[4], rq[4];
    const int wave = tid >> 6;
    if ((tid & 63) == 0) { rs[wave] = s; rq[wave] = sq; }
    __syncthreads();
    s  = rs[0] + rs[1] + rs[2] + rs[3];
    sq = rq[0] + rq[1] + rq[2] + rq[3];
    const float mean = s * (1.0f / D_MODEL);
    const float var  = sq * (1.0f / D_MODEL) - mean * mean;
    const float rstd = 1.0f / sqrtf(var + 1e-5f);
    const float4 wv = *reinterpret_cast<const float4*>(&w[tid * 4]);
    const float4 bv = *reinterpret_cast<const float4*>(&b[tid * 4]);
    float4 yv;
    yv.x = (xv.x - mean) * rstd * wv.x + bv.x;
    yv.y = (xv.y - mean) * rstd * wv.y + bv.y;
    yv.z = (xv.z - mean) * rstd * wv.z + bv.z;
    yv.w = (xv.w - mean) * rstd * wv.w + bv.w;
    *reinterpret_cast<float4*>(&Y[(size_t)row * D_MODEL + tid * 4]) = yv;
}

extern "C" void kernel_launch(void* const* d_in, const int* in_sizes, int n_in,
                              void* d_out, int out_size, void* d_ws, size_t ws_size,
                              hipStream_t stream) {
    const float* x       = (const float*)d_in[0];
    const float* k_cache = (const float*)d_in[1];
    const float* v_cache = (const float*)d_in[2];
    const int*   kv_len  = (const int*)d_in[4];
    const float* qkv_w   = (const float*)d_in[6];
    const float* qkv_b   = (const float*)d_in[7];
    const float* out_w   = (const float*)d_in[8];
    const float* out_b   = (const float*)d_in[9];
    const float* ln1_w   = (const float*)d_in[10];
    const float* ln1_b   = (const float*)d_in[11];
    const float* ln2_w   = (const float*)d_in[12];
    const float* ln2_b   = (const float*)d_in[13];
    const float* mlp_w1  = (const float*)d_in[14];
    const float* mlp_b1  = (const float*)d_in[15];
    const float* mlp_w2  = (const float*)d_in[16];
    const float* mlp_b2  = (const float*)d_in[17];

    float* out = (float*)d_out;
    float* ws  = (float*)d_ws;
    float* qkv = ws;                  // 64*3072 = 196608
    float* o   = ws + 196608;         // 64*1024
    float* t1  = ws + 262144;         // 64*1024
    float* t2  = ws + 327680;         // 64*1024
    float* t3  = ws + 393216;         // 64*4096
    float* t4  = ws + 655360;         // 64*1024
    float* P   = ws + 720896;         // 2097152 floats (split-K partials)
    // attention partials alias P (disjoint in time):
    float* m_ws = P;                          // 8192
    float* s_ws = P + 8192;                   // 8192
    float* o_ws = P + 16384;                  // 8192*64 = 524288

    // ---- qkv = x @ qkv_w + qkv_b : K=1024, N=3072, KC=128 -> S=8 ----
    gemm64_part<128><<<dim3(48, 8), 256, 0, stream>>>(x, qkv_w, P, 1024, 3072);
    reduce_kernel<false,false><<<768, 256, 0, stream>>>(P, qkv_b, nullptr, qkv, 3072, 8);

    // ---- attention (flash-decode over 8 chunks of 256) ----
    attn_part<<<dim3(NB, NH, NC), 256, 0, stream>>>(qkv, k_cache, v_cache, kv_len, m_ws, s_ws, o_ws);
    attn_combine<<<dim3(NB, NH), 64, 0, stream>>>(m_ws, s_ws, o_ws, kv_len, o);

    // ---- t1 = x + o @ out_w + out_b : K=1024, N=1024, KC=64 -> S=16 ----
    gemm64_part<64><<<dim3(16, 16), 256, 0, stream>>>(o, out_w, P, 1024, 1024);
    reduce_kernel<false,true><<<256, 256, 0, stream>>>(P, out_b, x, t1, 1024, 16);

    // ---- t2 = LN1(t1) ----
    ln_kernel<<<64, 256, 0, stream>>>(t1, ln1_w, ln1_b, t2);

    // ---- t3 = relu(t2 @ mlp_w1 + mlp_b1) : K=1024, N=4096, KC=128 -> S=8 ----
    gemm64_part<128><<<dim3(64, 8), 256, 0, stream>>>(t2, mlp_w1, P, 1024, 4096);
    reduce_kernel<true,false><<<1024, 256, 0, stream>>>(P, mlp_b1, nullptr, t3, 4096, 8);

    // ---- t4 = t2 + t3 @ mlp_w2 + mlp_b2 : K=4096, N=1024, KC=128 -> S=32 ----
    gemm64_part<128><<<dim3(16, 32), 256, 0, stream>>>(t3, mlp_w2, P, 4096, 1024);
    reduce_kernel<false,true><<<256, 256, 0, stream>>>(P, mlp_b2, t2, t4, 1024, 32);

    // ---- out = LN2(t4) ----
    ln_kernel<<<64, 256, 0, stream>>>(t4, ln2_w, ln2_b, out);
}

// Round 6
// 275.358 us; speedup vs baseline: 1.7467x; 1.1053x over previous
//
#include <hip/hip_runtime.h>
#include <hip/hip_bf16.h>
#include <math.h>

#define D_MODEL 1024
#define NH 16
#define HD 64
#define TMAX 2048
#define DFF 4096
#define NB 64
#define ACS 256                 // attention chunk size (positions per block)
#define NC (TMAX / ACS)         // 8 chunks max

// ---- split-K GEMM partial: P[s][64][N] = X[64, k0:k0+KC] @ W[k0:k0+KC, N] ----
// KC=64, fully unrolled k-loop -> deep W-load pipelining (latency fix).
template<int KC>
__global__ void gemm64_part(const float* __restrict__ X,
                            const float* __restrict__ W,
                            float* __restrict__ P,
                            int K, int N) {
    const int tx = threadIdx.x & 63;
    const int ty = threadIdx.x >> 6;          // 0..3
    const int n  = blockIdx.x * 64 + tx;
    const int k0 = blockIdx.y * KC;

    __shared__ float Xs[64][KC];

    for (int idx = threadIdx.x; idx < 64 * (KC / 4); idx += 256) {
        const int b  = idx / (KC / 4);
        const int kk = (idx % (KC / 4)) * 4;
        *reinterpret_cast<float4*>(&Xs[b][kk]) =
            *reinterpret_cast<const float4*>(&X[(size_t)b * K + k0 + kk]);
    }
    __syncthreads();

    float acc[16] = {0.f,0.f,0.f,0.f,0.f,0.f,0.f,0.f,
                     0.f,0.f,0.f,0.f,0.f,0.f,0.f,0.f};
    const float* Wp = W + (size_t)k0 * N + n;
#pragma unroll
    for (int kk = 0; kk < KC; kk += 4) {
        const float w0 = Wp[(size_t)(kk+0) * N];
        const float w1 = Wp[(size_t)(kk+1) * N];
        const float w2 = Wp[(size_t)(kk+2) * N];
        const float w3 = Wp[(size_t)(kk+3) * N];
#pragma unroll
        for (int i = 0; i < 16; ++i) {
            const float4 xv = *reinterpret_cast<const float4*>(&Xs[ty*16 + i][kk]);
            acc[i] += xv.x*w0 + xv.y*w1 + xv.z*w2 + xv.w*w3;
        }
    }

    float* Pp = P + (size_t)blockIdx.y * 64 * N + n;
#pragma unroll
    for (int i = 0; i < 16; ++i)
        Pp[(size_t)(ty*16 + i) * N] = acc[i];
}

// ---- reduce S partials + bias (+relu) -> Y[64,N] ----------------------------
template<bool RELU>
__global__ void reduce_kernel(const float* __restrict__ P,
                              const float* __restrict__ bias,
                              float* __restrict__ Y,
                              int N, int S) {
    const int i = blockIdx.x * 256 + threadIdx.x;   // over 64*N
    const int n = i % N;
    float s = 0.0f;
    for (int ss = 0; ss < S; ++ss)
        s += P[(size_t)ss * 64 * N + i];
    s += bias[n];
    if (RELU)  s = fmaxf(s, 0.0f);
    Y[i] = s;
}

// ---- fused: reduce S partials + bias + resid, then LayerNorm -> Y[64,1024] --
template<int S>
__global__ void reduce_ln_kernel(const float* __restrict__ P,
                                 const float* __restrict__ bias,
                                 const float* __restrict__ resid,
                                 const float* __restrict__ lnw,
                                 const float* __restrict__ lnb,
                                 float* __restrict__ Y) {
    const int b   = blockIdx.x;
    const int tid = threadIdx.x;
    float v[4];
    float s = 0.f, sq = 0.f;
#pragma unroll
    for (int jj = 0; jj < 4; ++jj) {
        const int n = jj * 256 + tid;
        float t = bias[n] + resid[(size_t)b * D_MODEL + n];
#pragma unroll
        for (int ss = 0; ss < S; ++ss)
            t += P[((size_t)ss * 64 + b) * D_MODEL + n];
        v[jj] = t; s += t; sq += t * t;
    }
    for (int off = 1; off < 64; off <<= 1) {
        s  += __shfl_xor(s, off);
        sq += __shfl_xor(sq, off);
    }
    __shared__ float rs[4], rq[4];
    const int wave = tid >> 6;
    if ((tid & 63) == 0) { rs[wave] = s; rq[wave] = sq; }
    __syncthreads();
    s  = rs[0] + rs[1] + rs[2] + rs[3];
    sq = rq[0] + rq[1] + rq[2] + rq[3];
    const float mean = s * (1.0f / D_MODEL);
    const float var  = sq * (1.0f / D_MODEL) - mean * mean;
    const float rstd = rsqrtf(var + 1e-5f);
#pragma unroll
    for (int jj = 0; jj < 4; ++jj) {
        const int n = jj * 256 + tid;
        Y[(size_t)b * D_MODEL + n] = (v[jj] - mean) * rstd * lnw[n] + lnb[n];
    }
}

// ---- flash-decode partial: one block per (b, h, chunk of 256) ---------------
// (round-5 verbatim — measured-good)
__global__ void attn_part(const float* __restrict__ qkv,
                          const float* __restrict__ k_cache,
                          const float* __restrict__ v_cache,
                          const int* __restrict__ kv_len,
                          float* __restrict__ m_ws,
                          float* __restrict__ s_ws,
                          float* __restrict__ o_ws) {
    const int b = blockIdx.x;
    const int h = blockIdx.y;
    const int c = blockIdx.z;
    const int tid = threadIdx.x; // 256

    const int L  = kv_len[b];
    const int nt = L + 1;
    const int c0 = c * ACS;
    if (c0 >= nt) return;                       // inactive chunk: no writes
    const int tend = min(ACS, nt - c0);
    const bool full = (c0 + ACS <= L);          // all 256 rows straight from cache

    __shared__ float q_s[HD];
    __shared__ float p_s[ACS];
    __shared__ float red[8];
    __shared__ float ored[16][HD + 4];

    const float* qkv_row = qkv + (size_t)b * (3 * D_MODEL);
    if (tid < HD) q_s[tid] = qkv_row[h * HD + tid] * 0.125f; // 1/sqrt(64)
    __syncthreads();

    const size_t bh = ((size_t)b * NH + h) * (size_t)TMAX * HD;
    const float* kc   = k_cache + bh + (size_t)c0 * HD;
    const float* vc   = v_cache + bh + (size_t)c0 * HD;
    const float* knew = qkv_row + D_MODEL     + h * HD;
    const float* vnew = qkv_row + 2 * D_MODEL + h * HD;
    const int Lloc = L - c0;

    // ---- scores: 16 lanes per row; rows rg, rg+16, ..., rg+240 ----
    const int rg = tid >> 4, l16 = tid & 15;
    const float4 qf = *reinterpret_cast<const float4*>(&q_s[l16 * 4]);
    if (full) {
        float4 kf[16];
#pragma unroll
        for (int j = 0; j < 16; ++j)
            kf[j] = *reinterpret_cast<const float4*>(&kc[(size_t)(rg + j * 16) * HD + l16 * 4]);
#pragma unroll
        for (int j = 0; j < 16; ++j) {
            float d = qf.x*kf[j].x + qf.y*kf[j].y + qf.z*kf[j].z + qf.w*kf[j].w;
            d += __shfl_xor(d, 1);
            d += __shfl_xor(d, 2);
            d += __shfl_xor(d, 4);
            d += __shfl_xor(d, 8);
            if (l16 == 0) p_s[rg + j * 16] = d;
        }
    } else {
        for (int t = rg; t < tend; t += 16) {
            const float* krow = (t == Lloc) ? knew : (kc + (size_t)t * HD);
            const float4 kf = *reinterpret_cast<const float4*>(&krow[l16 * 4]);
            float d = qf.x*kf.x + qf.y*kf.y + qf.z*kf.z + qf.w*kf.w;
            d += __shfl_xor(d, 1);
            d += __shfl_xor(d, 2);
            d += __shfl_xor(d, 4);
            d += __shfl_xor(d, 8);
            if (l16 == 0) p_s[t] = d;
        }
    }

    // ---- V prefetch to registers (independent of scores/softmax) ----
    const int d4 = tid & 15, r = tid >> 4;      // dim-quad, row-in-stride
    float4 vreg[16];
    if (full) {
#pragma unroll
        for (int j = 0; j < 16; ++j)
            vreg[j] = *reinterpret_cast<const float4*>(&vc[(size_t)(r + j * 16) * HD + d4 * 4]);
    } else {
#pragma unroll
        for (int j = 0; j < 16; ++j) {
            const int t = r + j * 16;
            if (t < tend) {
                const float* vrow = (t == Lloc) ? vnew : (vc + (size_t)t * HD);
                vreg[j] = *reinterpret_cast<const float4*>(&vrow[d4 * 4]);
            } else {
                vreg[j] = make_float4(0.f, 0.f, 0.f, 0.f);
            }
        }
    }
    __syncthreads();    // p_s complete

    // ---- softmax stats: exactly one element per thread ----
    const float pv = (tid < tend) ? p_s[tid] : -INFINITY;
    float m = pv;
    for (int off = 1; off < 64; off <<= 1) m = fmaxf(m, __shfl_xor(m, off));
    const int wave = tid >> 6;
    if ((tid & 63) == 0) red[wave] = m;
    __syncthreads();
    m = fmaxf(fmaxf(red[0], red[1]), fmaxf(red[2], red[3]));

    float e = (tid < tend) ? expf(pv - m) : 0.0f;
    p_s[tid] = e;                                // zero-fill beyond tend
    float s = e;
    for (int off = 1; off < 64; off <<= 1) s += __shfl_xor(s, off);
    if ((tid & 63) == 0) red[4 + wave] = s;
    __syncthreads();
    const float ssum = red[4] + red[5] + red[6] + red[7];

    // ---- unnormalized P@V from registers ----
    float4 acc = make_float4(0.f, 0.f, 0.f, 0.f);
#pragma unroll
    for (int j = 0; j < 16; ++j) {
        const float p = p_s[r + j * 16];
        acc.x += p * vreg[j].x; acc.y += p * vreg[j].y;
        acc.z += p * vreg[j].z; acc.w += p * vreg[j].w;
    }
    *reinterpret_cast<float4*>(&ored[r][d4 * 4]) = acc;
    __syncthreads();

    const size_t idx = ((size_t)b * NH + h) * NC + c;
    if (tid == 0) { m_ws[idx] = m; s_ws[idx] = ssum; }
    if (tid < HD) {
        float o = 0.0f;
#pragma unroll
        for (int g = 0; g < 16; ++g) o += ored[g][tid];
        o_ws[idx * HD + tid] = o;
    }
}

// ---- combine chunk partials -> o[b, h*HD + d] -------------------------------
__global__ void attn_combine(const float* __restrict__ m_ws,
                             const float* __restrict__ s_ws,
                             const float* __restrict__ o_ws,
                             const int* __restrict__ kv_len,
                             float* __restrict__ o) {
    const int b = blockIdx.x;
    const int h = blockIdx.y;
    const int d = threadIdx.x;  // 64
    const int nt = kv_len[b] + 1;
    const int nc = (nt + ACS - 1) / ACS;
    const size_t idx0 = ((size_t)b * NH + h) * NC;

    float M = -INFINITY;
    for (int c = 0; c < nc; ++c) M = fmaxf(M, m_ws[idx0 + c]);
    float den = 0.0f, num = 0.0f;
    for (int c = 0; c < nc; ++c) {
        const float w = expf(m_ws[idx0 + c] - M);
        den += w * s_ws[idx0 + c];
        num += w * o_ws[(idx0 + c) * HD + d];
    }
    o[(size_t)b * D_MODEL + h * HD + d] = num / den;
}

extern "C" void kernel_launch(void* const* d_in, const int* in_sizes, int n_in,
                              void* d_out, int out_size, void* d_ws, size_t ws_size,
                              hipStream_t stream) {
    const float* x       = (const float*)d_in[0];
    const float* k_cache = (const float*)d_in[1];
    const float* v_cache = (const float*)d_in[2];
    const int*   kv_len  = (const int*)d_in[4];
    const float* qkv_w   = (const float*)d_in[6];
    const float* qkv_b   = (const float*)d_in[7];
    const float* out_w   = (const float*)d_in[8];
    const float* out_b   = (const float*)d_in[9];
    const float* ln1_w   = (const float*)d_in[10];
    const float* ln1_b   = (const float*)d_in[11];
    const float* ln2_w   = (const float*)d_in[12];
    const float* ln2_b   = (const float*)d_in[13];
    const float* mlp_w1  = (const float*)d_in[14];
    const float* mlp_b1  = (const float*)d_in[15];
    const float* mlp_w2  = (const float*)d_in[16];
    const float* mlp_b2  = (const float*)d_in[17];

    float* out = (float*)d_out;
    float* ws  = (float*)d_ws;
    float* qkv = ws;                  // 64*3072 = 196608
    float* o   = ws + 196608;         // 64*1024
    float* t2  = ws + 262144;         // 64*1024
    float* t3  = ws + 327680;         // 64*4096
    float* P   = ws + 589824;         // split-K partials (up to 64 slabs)
    // attention partials alias P (disjoint in time):
    float* m_ws = P;                          // 8192
    float* s_ws = P + 8192;                   // 8192
    float* o_ws = P + 16384;                  // 8192*64 = 524288

    // ---- qkv = x @ qkv_w + qkv_b : K=1024, N=3072, KC=64 -> S=16 ----
    gemm64_part<64><<<dim3(48, 16), 256, 0, stream>>>(x, qkv_w, P, 1024, 3072);
    reduce_kernel<false><<<768, 256, 0, stream>>>(P, qkv_b, qkv, 3072, 16);

    // ---- attention (flash-decode over 8 chunks of 256) ----
    attn_part<<<dim3(NB, NH, NC), 256, 0, stream>>>(qkv, k_cache, v_cache, kv_len, m_ws, s_ws, o_ws);
    attn_combine<<<dim3(NB, NH), 64, 0, stream>>>(m_ws, s_ws, o_ws, kv_len, o);

    // ---- t2 = LN1(x + o @ out_w + out_b) : K=1024, N=1024, KC=64 -> S=16 ----
    gemm64_part<64><<<dim3(16, 16), 256, 0, stream>>>(o, out_w, P, 1024, 1024);
    reduce_ln_kernel<16><<<64, 256, 0, stream>>>(P, out_b, x, ln1_w, ln1_b, t2);

    // ---- t3 = relu(t2 @ mlp_w1 + mlp_b1) : K=1024, N=4096, KC=64 -> S=16 ----
    gemm64_part<64><<<dim3(64, 16), 256, 0, stream>>>(t2, mlp_w1, P, 1024, 4096);
    reduce_kernel<true><<<1024, 256, 0, stream>>>(P, mlp_b1, t3, 4096, 16);

    // ---- out = LN2(t2 + t3 @ mlp_w2 + mlp_b2) : K=4096, N=1024, KC=64 -> S=64
    gemm64_part<64><<<dim3(16, 64), 256, 0, stream>>>(t3, mlp_w2, P, 4096, 1024);
    reduce_ln_kernel<64><<<64, 256, 0, stream>>>(P, mlp_b2, t2, ln2_w, ln2_b, out);
}